// Round 5
// baseline (807.026 us; speedup 1.0000x reference)
//
#include <hip/hip_runtime.h>

#define N_NODES 50000
#define N_EDGES 1600000
#define F 11
#define FEAT 27   // 2F + 1 + ED
#define NLAYERS 4
#define NGRAPH 500
#define NVALS 14       // 11 msg_h + 3 msg_x
#define PRESTRIDE 24   // padded pre-table row: m[0..12), x[12..24)
#define NBLK 196       // ceil(N_NODES/256)

__device__ __forceinline__ float siluf(float v) { return v * (1.0f / (1.0f + __expf(-v))); }
__device__ __forceinline__ float sigmf(float v) { return 1.0f / (1.0f + __expf(-v)); }

// packed fp32 FMA: d.lo = a.lo*b.lo+c.lo ; d.hi = a.hi*b.hi+c.hi  (exact fp32)
__device__ __forceinline__ float2 pkfma(float2 a, float2 b, float2 c) {
    float2 d;
    asm("v_pk_fma_f32 %0, %1, %2, %3" : "=v"(d) : "v"(a), "v"(b), "v"(c));
    return d;
}
__device__ __forceinline__ void rank1_pk(float v, const float4 w, float2& a0, float2& a1) {
    float2 vv = make_float2(v, v);
    a0 = pkfma(vv, make_float2(w.x, w.y), a0);
    a1 = pkfma(vv, make_float2(w.z, w.w), a1);
}

// ---------- one-time edge sort by dst (counting sort) ----------
__global__ __launch_bounds__(256) void hist_kernel(const int* __restrict__ dst,
                                                   int* __restrict__ deg) {
    int e = blockIdx.x * 256 + threadIdx.x;
    if (e < N_EDGES) atomicAdd(&deg[dst[e]], 1);
}

__global__ __launch_bounds__(256) void scan1_kernel(const int* __restrict__ deg,
                                                    int* __restrict__ part,
                                                    int* __restrict__ bsum) {
    int t = threadIdx.x;
    int i = blockIdx.x * 256 + t;
    int v = (i < N_NODES) ? deg[i] : 0;
    int lane = t & 63, wid = t >> 6;
    int s = v;
    #pragma unroll
    for (int off = 1; off < 64; off <<= 1) {
        int u = __shfl_up(s, off);
        if (lane >= off) s += u;
    }
    __shared__ int wsum[4];
    if (lane == 63) wsum[wid] = s;
    __syncthreads();
    int wpre = 0;
    #pragma unroll
    for (int w = 0; w < 4; ++w) if (w < wid) wpre += wsum[w];
    if (i < N_NODES) part[i] = s + wpre - v;
    if (t == 255) bsum[blockIdx.x] = s + wpre;
}

__global__ __launch_bounds__(256) void scan2_kernel(int* __restrict__ bsum) {
    int t = threadIdx.x;
    int v = (t < NBLK) ? bsum[t] : 0;
    int lane = t & 63, wid = t >> 6;
    int s = v;
    #pragma unroll
    for (int off = 1; off < 64; off <<= 1) {
        int u = __shfl_up(s, off);
        if (lane >= off) s += u;
    }
    __shared__ int wsum[4];
    if (lane == 63) wsum[wid] = s;
    __syncthreads();
    int wpre = 0;
    #pragma unroll
    for (int w = 0; w < 4; ++w) if (w < wid) wpre += wsum[w];
    if (t < NBLK) bsum[t] = s + wpre - v;
}

__global__ __launch_bounds__(256) void scan3_kernel(const int* __restrict__ part,
                                                    const int* __restrict__ bsum,
                                                    int* __restrict__ cursor) {
    int i = blockIdx.x * 256 + threadIdx.x;
    if (i < N_NODES) cursor[i] = part[i] + bsum[blockIdx.x];
}

// write only the permutation (4B random writes instead of 24B)
__global__ __launch_bounds__(256) void scatter_perm(const int* __restrict__ dst,
                                                    int* __restrict__ cursor,
                                                    int* __restrict__ perm) {
    int e = blockIdx.x * 256 + threadIdx.x;
    if (e >= N_EDGES) return;
    int d = dst[e];
    int pos = atomicAdd(&cursor[d], 1);
    perm[pos] = e;
}

// gather-materialize sorted arrays with coalesced writes
__global__ __launch_bounds__(256) void mat_kernel(
    const int* __restrict__ perm, const int* __restrict__ src,
    const int* __restrict__ dst, const float4* __restrict__ eattr4,
    int* __restrict__ ssrc, int* __restrict__ sdst, float4* __restrict__ sea) {
    int i = blockIdx.x * 256 + threadIdx.x;
    if (i >= N_EDGES) return;
    int e = perm[i];
    ssrc[i] = src[e];
    sdst[i] = dst[e];
    sea[i] = eattr4[e];
}

// ---------- init: copy state + layer-0 per-node precompute ----------
// preA[n][0:11]  = h@Wm1[0:F]+bm1 ; [11]=0 ; [12:23] = h@Wx1[0:F]+bx1 ; [23]=0
// preB[n]: same with Wm1[F:2F]/Wx1[F:2F], no bias
__global__ __launch_bounds__(256) void init_kernel(
    const float* __restrict__ h0, const float* __restrict__ pos,
    float* __restrict__ h, float* __restrict__ x,
    const float* __restrict__ Wm1, const float* __restrict__ bm1,
    const float* __restrict__ Wx1, const float* __restrict__ bx1,
    float* __restrict__ preA, float* __restrict__ preB)
{
    __shared__ float sM[2 * F * F], sX[2 * F * F], sbm[F], sbx[F];
    int t = threadIdx.x;
    for (int i2 = t; i2 < 2 * F * F; i2 += 256) { sM[i2] = Wm1[i2]; sX[i2] = Wx1[i2]; }
    if (t < F) { sbm[t] = bm1[t]; sbx[t] = bx1[t]; }
    __syncthreads();

    int n = blockIdx.x * 256 + t;
    if (n >= N_NODES) return;

    float hv[F];
    #pragma unroll
    for (int f2 = 0; f2 < F; ++f2) { hv[f2] = h0[n * F + f2]; h[n * F + f2] = hv[f2]; }
    #pragma unroll
    for (int k = 0; k < 3; ++k) x[n * 3 + k] = pos[n * 3 + k];

    float am[F], bm_[F], ax[F], bx_[F];
    #pragma unroll
    for (int o = 0; o < F; ++o) { am[o] = sbm[o]; ax[o] = sbx[o]; bm_[o] = 0.f; bx_[o] = 0.f; }
    #pragma unroll
    for (int fi = 0; fi < F; ++fi) {
        float v = hv[fi];
        #pragma unroll
        for (int o = 0; o < F; ++o) {
            am[o]  = fmaf(v, sM[fi * F + o], am[o]);
            bm_[o] = fmaf(v, sM[(F + fi) * F + o], bm_[o]);
            ax[o]  = fmaf(v, sX[fi * F + o], ax[o]);
            bx_[o] = fmaf(v, sX[(F + fi) * F + o], bx_[o]);
        }
    }
    #pragma unroll
    for (int o = 0; o < F; ++o) {
        preA[n * PRESTRIDE + o]      = am[o];
        preA[n * PRESTRIDE + 12 + o] = ax[o];
        preB[n * PRESTRIDE + o]      = bm_[o];
        preB[n * PRESTRIDE + 12 + o] = bx_[o];
    }
    preA[n * PRESTRIDE + 11] = 0.f; preA[n * PRESTRIDE + 23] = 0.f;
    preB[n * PRESTRIDE + 11] = 0.f; preB[n * PRESTRIDE + 23] = 0.f;
}

// ---------- per-layer edge kernel on dst-sorted edges ----------
__global__ __launch_bounds__(256) void edge_kernel(
    const float* __restrict__ preA, const float* __restrict__ preB,
    const float* __restrict__ x,
    const int* __restrict__ ssrc, const int* __restrict__ sdst,
    const float4* __restrict__ sea,
    const float* __restrict__ Wm1,                                  // rows 22..26
    const float* __restrict__ Wm2, const float* __restrict__ bm2,
    const float* __restrict__ Wa,  const float* __restrict__ ba,
    const float* __restrict__ Wx1,                                  // rows 22..26
    const float* __restrict__ Wx2, const float* __restrict__ bx2,
    const float* __restrict__ Wx3, const float* __restrict__ bx3,
    float* __restrict__ agg_h, float* __restrict__ agg_x)
{
    // all weight rows padded to 12 floats (3 x float4)
    __shared__ float4 sW2m[F * 3], sW2x[F * 3];
    __shared__ float4 sD2m[3], sD2x[3], sEAm[4 * 3], sEAx[4 * 3];
    __shared__ float4 sB2m[3], sB2x[3], sWav[3], sWx3v[3];
    __shared__ float sba, sbx3;
    int t = threadIdx.x;
    {
        float* w2m = (float*)sW2m; float* w2x = (float*)sW2x;
        for (int i2 = t; i2 < F * 12; i2 += 256) {
            int r = i2 / 12, c = i2 % 12;
            w2m[i2] = (c < F) ? Wm2[r * F + c] : 0.f;
            w2x[i2] = (c < F) ? Wx2[r * F + c] : 0.f;
        }
        float* eam = (float*)sEAm; float* eax = (float*)sEAx;
        for (int i2 = t; i2 < 4 * 12; i2 += 256) {
            int r = i2 / 12, c = i2 % 12;
            eam[i2] = (c < F) ? Wm1[(23 + r) * F + c] : 0.f;
            eax[i2] = (c < F) ? Wx1[(23 + r) * F + c] : 0.f;
        }
        if (t < 12) {
            ((float*)sD2m)[t] = (t < F) ? Wm1[22 * F + t] : 0.f;
            ((float*)sD2x)[t] = (t < F) ? Wx1[22 * F + t] : 0.f;
            ((float*)sB2m)[t] = (t < F) ? bm2[t] : 0.f;
            ((float*)sB2x)[t] = (t < F) ? bx2[t] : 0.f;
            ((float*)sWav)[t] = (t < F) ? Wa[t] : 0.f;
            ((float*)sWx3v)[t] = (t < F) ? Wx3[t] : 0.f;
        }
        if (t == 0) { sba = ba[0]; sbx3 = bx3[0]; }
    }
    __syncthreads();

    int e = blockIdx.x * 256 + t;
    if (e >= N_EDGES) return;

    int j = ssrc[e];   // source
    int d = sdst[e];   // target (sorted ascending)

    float4 pa[6], pb[6];
    {
        const float4* pa4 = reinterpret_cast<const float4*>(preA + (size_t)d * PRESTRIDE);
        const float4* pb4 = reinterpret_cast<const float4*>(preB + (size_t)j * PRESTRIDE);
        #pragma unroll
        for (int q = 0; q < 6; ++q) { pa[q] = pa4[q]; pb[q] = pb4[q]; }
    }

    float xi0 = x[d * 3 + 0], xi1 = x[d * 3 + 1], xi2 = x[d * 3 + 2];
    float xj0 = x[j * 3 + 0], xj1 = x[j * 3 + 1], xj2 = x[j * 3 + 2];
    float dx = xj0 - xi0, dy = xj1 - xi1, dz = xj2 - xi2;
    float d2 = dx * dx + dy * dy + dz * dz;
    float4 ea = sea[e];

    // layer-1 accumulators (padded 12 = 6 x float2) : node parts + d2 + ea terms
    float2 am[6], axv[6];
    #pragma unroll
    for (int q = 0; q < 3; ++q) {
        float4 sm, sx;
        sm.x = pa[q].x + pb[q].x; sm.y = pa[q].y + pb[q].y;
        sm.z = pa[q].z + pb[q].z; sm.w = pa[q].w + pb[q].w;
        sx.x = pa[3 + q].x + pb[3 + q].x; sx.y = pa[3 + q].y + pb[3 + q].y;
        sx.z = pa[3 + q].z + pb[3 + q].z; sx.w = pa[3 + q].w + pb[3 + q].w;
        am[2 * q]     = make_float2(sm.x, sm.y);
        am[2 * q + 1] = make_float2(sm.z, sm.w);
        axv[2 * q]     = make_float2(sx.x, sx.y);
        axv[2 * q + 1] = make_float2(sx.z, sx.w);
    }
    #pragma unroll
    for (int qq = 0; qq < 3; ++qq) {
        rank1_pk(d2, sD2m[qq], am[2 * qq], am[2 * qq + 1]);
        rank1_pk(d2, sD2x[qq], axv[2 * qq], axv[2 * qq + 1]);
    }
    float eav[4] = {ea.x, ea.y, ea.z, ea.w};
    #pragma unroll
    for (int k = 0; k < 4; ++k) {
        #pragma unroll
        for (int qq = 0; qq < 3; ++qq) {
            rank1_pk(eav[k], sEAm[k * 3 + qq], am[2 * qq], am[2 * qq + 1]);
            rank1_pk(eav[k], sEAx[k * 3 + qq], axv[2 * qq], axv[2 * qq + 1]);
        }
    }

    // silu
    float tm[12], tx[12];
    #pragma unroll
    for (int q = 0; q < 6; ++q) {
        tm[2 * q] = am[q].x; tm[2 * q + 1] = am[q].y;
        tx[2 * q] = axv[q].x; tx[2 * q + 1] = axv[q].y;
    }
    #pragma unroll
    for (int o = 0; o < F; ++o) { tm[o] = siluf(tm[o]); tx[o] = siluf(tx[o]); }

    // layer-2 (packed)
    float2 m2a[6], p2a[6];
    {
        const float2* b2m = (const float2*)sB2m;
        const float2* b2x = (const float2*)sB2x;
        #pragma unroll
        for (int q = 0; q < 6; ++q) { m2a[q] = b2m[q]; p2a[q] = b2x[q]; }
    }
    #pragma unroll
    for (int fi = 0; fi < F; ++fi) {
        float a = tm[fi], b = tx[fi];
        #pragma unroll
        for (int qq = 0; qq < 3; ++qq) {
            rank1_pk(a, sW2m[fi * 3 + qq], m2a[2 * qq], m2a[2 * qq + 1]);
            rank1_pk(b, sW2x[fi * 3 + qq], p2a[2 * qq], p2a[2 * qq + 1]);
        }
    }
    float m2s[12], p2s[12];
    #pragma unroll
    for (int q = 0; q < 6; ++q) {
        m2s[2 * q] = m2a[q].x; m2s[2 * q + 1] = m2a[q].y;
        p2s[2 * q] = p2a[q].x; p2s[2 * q + 1] = p2a[q].y;
    }
    #pragma unroll
    for (int o = 0; o < F; ++o) { m2s[o] = siluf(m2s[o]); p2s[o] = siluf(p2s[o]); }
    m2s[11] = 0.f; p2s[11] = 0.f;

    // heads (packed dot)
    float2 accA = make_float2(0.f, 0.f), accP = make_float2(0.f, 0.f);
    {
        const float2* wa = (const float2*)sWav;
        const float2* w3 = (const float2*)sWx3v;
        #pragma unroll
        for (int q = 0; q < 6; ++q) {
            accA = pkfma(make_float2(m2s[2 * q], m2s[2 * q + 1]), wa[q], accA);
            accP = pkfma(make_float2(p2s[2 * q], p2s[2 * q + 1]), w3[q], accP);
        }
    }
    float attn = sigmf(sba + accA.x + accA.y);
    float phi  = sbx3 + accP.x + accP.y;

    float dist = sqrtf(d2);
    float sc = phi / (dist + 1.0f);

    float vals[NVALS];
    #pragma unroll
    for (int o = 0; o < F; ++o) vals[o] = attn * m2s[o];
    vals[F + 0] = (xi0 - xj0) * sc;
    vals[F + 1] = (xi1 - xj1) * sc;
    vals[F + 2] = (xi2 - xj2) * sc;

    // wave-level segmented suffix reduction (keys sorted within wave)
    int lane = t & 63;
    #pragma unroll
    for (int off = 1; off < 64; off <<= 1) {
        int du = __shfl_down(d, off);
        bool ok = (lane + off < 64) && (du == d);
        #pragma unroll
        for (int k = 0; k < NVALS; ++k) {
            float up = __shfl_down(vals[k], off);
            if (ok) vals[k] += up;
        }
    }
    int dprev = __shfl_up(d, 1);
    if (lane == 0 || dprev != d) {
        #pragma unroll
        for (int o = 0; o < F; ++o) unsafeAtomicAdd(&agg_h[d * F + o], vals[o]);
        unsafeAtomicAdd(&agg_x[d * 3 + 0], vals[F + 0]);
        unsafeAtomicAdd(&agg_x[d * 3 + 1], vals[F + 1]);
        unsafeAtomicAdd(&agg_x[d * 3 + 2], vals[F + 2]);
    }
}

// ---------- node update + fused precompute for next layer ----------
__global__ __launch_bounds__(256) void node_kernel(
    float* __restrict__ h, float* __restrict__ x,
    const float* __restrict__ agg_h, const float* __restrict__ agg_x,
    const float* __restrict__ Wu1, const float* __restrict__ bu1,
    const float* __restrict__ Wu2, const float* __restrict__ bu2,
    const float* __restrict__ Wm1n, const float* __restrict__ bm1n,
    const float* __restrict__ Wx1n, const float* __restrict__ bx1n,
    float* __restrict__ preA, float* __restrict__ preB, int has_next)
{
    __shared__ float sWu1[2 * F * F], sWu2[F * F], sbu1[F], sbu2[F];
    __shared__ float sM[2 * F * F], sX[2 * F * F], sbm[F], sbx[F];
    int t = threadIdx.x;
    for (int i2 = t; i2 < 2 * F * F; i2 += 256) sWu1[i2] = Wu1[i2];
    for (int i2 = t; i2 < F * F; i2 += 256)     sWu2[i2] = Wu2[i2];
    if (t < F) { sbu1[t] = bu1[t]; sbu2[t] = bu2[t]; }
    if (has_next) {
        for (int i2 = t; i2 < 2 * F * F; i2 += 256) { sM[i2] = Wm1n[i2]; sX[i2] = Wx1n[i2]; }
        if (t < F) { sbm[t] = bm1n[t]; sbx[t] = bx1n[t]; }
    }
    __syncthreads();

    int n = blockIdx.x * 256 + t;
    if (n >= N_NODES) return;

    float in[2 * F];
    #pragma unroll
    for (int f2 = 0; f2 < F; ++f2) in[f2] = h[n * F + f2];
    #pragma unroll
    for (int f2 = 0; f2 < F; ++f2) in[F + f2] = agg_h[n * F + f2];

    float u[F];
    #pragma unroll
    for (int o = 0; o < F; ++o) u[o] = sbu1[o];
    #pragma unroll
    for (int fi = 0; fi < 2 * F; ++fi) {
        float fv = in[fi];
        #pragma unroll
        for (int o = 0; o < F; ++o) u[o] = fmaf(fv, sWu1[fi * F + o], u[o]);
    }
    #pragma unroll
    for (int o = 0; o < F; ++o) u[o] = siluf(u[o]);

    float hn[F];
    #pragma unroll
    for (int o = 0; o < F; ++o) hn[o] = in[o] + sbu2[o];
    #pragma unroll
    for (int fi = 0; fi < F; ++fi) {
        float fv = u[fi];
        #pragma unroll
        for (int o = 0; o < F; ++o) hn[o] = fmaf(fv, sWu2[fi * F + o], hn[o]);
    }

    #pragma unroll
    for (int f2 = 0; f2 < F; ++f2) h[n * F + f2] = hn[f2];
    #pragma unroll
    for (int k = 0; k < 3; ++k) x[n * 3 + k] += agg_x[n * 3 + k];

    if (has_next) {
        float am[F], bm_[F], ax[F], bx_[F];
        #pragma unroll
        for (int o = 0; o < F; ++o) { am[o] = sbm[o]; ax[o] = sbx[o]; bm_[o] = 0.f; bx_[o] = 0.f; }
        #pragma unroll
        for (int fi = 0; fi < F; ++fi) {
            float v = hn[fi];
            #pragma unroll
            for (int o = 0; o < F; ++o) {
                am[o]  = fmaf(v, sM[fi * F + o], am[o]);
                bm_[o] = fmaf(v, sM[(F + fi) * F + o], bm_[o]);
                ax[o]  = fmaf(v, sX[fi * F + o], ax[o]);
                bx_[o] = fmaf(v, sX[(F + fi) * F + o], bx_[o]);
            }
        }
        #pragma unroll
        for (int o = 0; o < F; ++o) {
            preA[n * PRESTRIDE + o]      = am[o];
            preA[n * PRESTRIDE + 12 + o] = ax[o];
            preB[n * PRESTRIDE + o]      = bm_[o];
            preB[n * PRESTRIDE + 12 + o] = bx_[o];
        }
        preA[n * PRESTRIDE + 11] = 0.f; preA[n * PRESTRIDE + 23] = 0.f;
        preB[n * PRESTRIDE + 11] = 0.f; preB[n * PRESTRIDE + 23] = 0.f;
    }
}

// ---------- pool ----------
__global__ __launch_bounds__(256) void pool_kernel(
    const float* __restrict__ h, const int* __restrict__ batch,
    float* __restrict__ gsum, float* __restrict__ gcnt)
{
    int n = blockIdx.x * blockDim.x + threadIdx.x;
    int lane = threadIdx.x & 63;
    bool valid = (n < N_NODES);
    int g = valid ? batch[n] : -1;
    float vals[F + 1];
    #pragma unroll
    for (int f2 = 0; f2 < F; ++f2) vals[f2] = valid ? h[n * F + f2] : 0.0f;
    vals[F] = valid ? 1.0f : 0.0f;

    #pragma unroll
    for (int off = 1; off < 64; off <<= 1) {
        int gu = __shfl_down(g, off);
        bool ok = (lane + off < 64) && (gu == g);
        #pragma unroll
        for (int k = 0; k < F + 1; ++k) {
            float up = __shfl_down(vals[k], off);
            if (ok) vals[k] += up;
        }
    }
    int gprev = __shfl_up(g, 1);
    if (valid && (lane == 0 || gprev != g)) {
        #pragma unroll
        for (int f2 = 0; f2 < F; ++f2) unsafeAtomicAdd(&gsum[g * F + f2], vals[f2]);
        unsafeAtomicAdd(&gcnt[g], vals[F]);
    }
}

__global__ void head_kernel(const float* __restrict__ gsum, const float* __restrict__ gcnt,
                            const float* __restrict__ Wp, const float* __restrict__ bp,
                            float* __restrict__ out)
{
    int g = blockIdx.x * blockDim.x + threadIdx.x;
    if (g >= NGRAPH) return;
    float c = fmaxf(gcnt[g], 1.0f);
    float inv = 1.0f / c;
    float acc = bp[0];
    #pragma unroll
    for (int f2 = 0; f2 < F; ++f2) acc = fmaf(gsum[g * F + f2] * inv, Wp[f2], acc);
    out[g] = acc;
}

extern "C" void kernel_launch(void* const* d_in, const int* in_sizes, int n_in,
                              void* d_out, int out_size, void* d_ws, size_t ws_size,
                              hipStream_t stream)
{
    const float* h0    = (const float*)d_in[0];
    const float* pos   = (const float*)d_in[1];
    const int*   eidx  = (const int*)d_in[2];
    const float* eattr = (const float*)d_in[3];
    const int*   batch = (const int*)d_in[4];
    const float* Wm1 = (const float*)d_in[5];
    const float* bm1 = (const float*)d_in[6];
    const float* Wm2 = (const float*)d_in[7];
    const float* bm2 = (const float*)d_in[8];
    const float* Wa  = (const float*)d_in[9];
    const float* ba  = (const float*)d_in[10];
    const float* Wu1 = (const float*)d_in[11];
    const float* bu1 = (const float*)d_in[12];
    const float* Wu2 = (const float*)d_in[13];
    const float* bu2 = (const float*)d_in[14];
    const float* Wx1 = (const float*)d_in[15];
    const float* bx1 = (const float*)d_in[16];
    const float* Wx2 = (const float*)d_in[17];
    const float* bx2 = (const float*)d_in[18];
    const float* Wx3 = (const float*)d_in[19];
    const float* bx3 = (const float*)d_in[20];
    const float* Wp  = (const float*)d_in[21];
    const float* bp  = (const float*)d_in[22];

    char* base = (char*)d_ws;
    float4* sea  = (float4*)base;                         base += (size_t)N_EDGES * 16;
    float* preA  = (float*)base;                          base += (size_t)N_NODES * PRESTRIDE * 4;
    float* preB  = (float*)base;                          base += (size_t)N_NODES * PRESTRIDE * 4;
    float* h_cur = (float*)base;                          base += (size_t)N_NODES * F * 4;
    float* x_cur = (float*)base;                          base += (size_t)N_NODES * 3 * 4;
    float* agg_h = (float*)base;                          base += (size_t)N_NODES * F * 4;
    float* agg_x = (float*)base;                          base += (size_t)N_NODES * 3 * 4;
    float* gsum  = (float*)base;                          base += (size_t)NGRAPH * F * 4;
    float* gcnt  = (float*)base;                          base += (size_t)NGRAPH * 4;
    int*   deg   = (int*)base;                            base += (size_t)N_NODES * 4;
    int*   part  = (int*)base;                            base += (size_t)N_NODES * 4;
    int*   bsum  = (int*)base;                            base += (size_t)256 * 4;
    int*   cursor= (int*)base;                            base += (size_t)N_NODES * 4;
    int*   perm  = (int*)base;                            base += (size_t)N_EDGES * 4;
    int*   ssrc  = (int*)base;                            base += (size_t)N_EDGES * 4;
    int*   sdst  = (int*)base;                            base += (size_t)N_EDGES * 4;

    const int* src = eidx;            // edge_index[0]
    const int* dst = eidx + N_EDGES;  // edge_index[1]

    // one-time: counting sort of edges by dst
    hipMemsetAsync(deg, 0, (size_t)N_NODES * sizeof(int), stream);
    hist_kernel<<<(N_EDGES + 255) / 256, 256, 0, stream>>>(dst, deg);
    scan1_kernel<<<NBLK, 256, 0, stream>>>(deg, part, bsum);
    scan2_kernel<<<1, 256, 0, stream>>>(bsum);
    scan3_kernel<<<NBLK, 256, 0, stream>>>(part, bsum, cursor);
    scatter_perm<<<(N_EDGES + 255) / 256, 256, 0, stream>>>(dst, cursor, perm);
    mat_kernel<<<(N_EDGES + 255) / 256, 256, 0, stream>>>(
        perm, src, dst, reinterpret_cast<const float4*>(eattr), ssrc, sdst, sea);

    init_kernel<<<NBLK, 256, 0, stream>>>(h0, pos, h_cur, x_cur,
                                          Wm1, bm1, Wx1, bx1, preA, preB);

    for (int l = 0; l < NLAYERS; ++l) {
        hipMemsetAsync(agg_h, 0, (size_t)(N_NODES * (F + 3)) * sizeof(float), stream);
        edge_kernel<<<(N_EDGES + 255) / 256, 256, 0, stream>>>(
            preA, preB, x_cur, ssrc, sdst, sea,
            Wm1 + l * FEAT * F,
            Wm2 + l * F * F,    bm2 + l * F,
            Wa + l * F,         ba + l,
            Wx1 + l * FEAT * F,
            Wx2 + l * F * F,    bx2 + l * F,
            Wx3 + l * F,        bx3 + l,
            agg_h, agg_x);
        int nl = l + 1;
        int has_next = (nl < NLAYERS) ? 1 : 0;
        int wl = has_next ? nl : l;
        node_kernel<<<NBLK, 256, 0, stream>>>(
            h_cur, x_cur, agg_h, agg_x,
            Wu1 + l * 2 * F * F, bu1 + l * F,
            Wu2 + l * F * F,     bu2 + l * F,
            Wm1 + wl * FEAT * F, bm1 + wl * F,
            Wx1 + wl * FEAT * F, bx1 + wl * F,
            preA, preB, has_next);
    }

    hipMemsetAsync(gsum, 0, (size_t)(NGRAPH * F + NGRAPH) * sizeof(float), stream);
    pool_kernel<<<(N_NODES + 255) / 256, 256, 0, stream>>>(h_cur, batch, gsum, gcnt);
    head_kernel<<<2, 256, 0, stream>>>(gsum, gcnt, Wp, bp, (float*)d_out);
}